// Round 2
// baseline (11218.061 us; speedup 1.0000x reference)
//
#include <hip/hip_runtime.h>

#define N_NODES 50000
#define N_EDGES 800000
#define PDIM 3
#define FDIM 64
#define MDIM 32
#define NLAYERS 2
#define EINDIM 129      // 2F+1
#define H1 258          // 2*EIN
#define CH 128          // 4*M
#define NH 128          // 2*F
#define XDIM 67         // P+F
#define W1P_HALF 132    // 129 cols padded to 132 (float4-aligned)
#define W1P_STRIDE 264  // two halves

__device__ __forceinline__ float fsilu(float x) {
  return x / (1.0f + __expf(-x));
}

__device__ __forceinline__ unsigned short f2bf(float f) {
  union { float f; unsigned u; } v; v.f = f;
  unsigned r = v.u + 0x7FFF + ((v.u >> 16) & 1);  // RNE
  return (unsigned short)(r >> 16);
}

__device__ __forceinline__ float bf2f(unsigned short u) {
  union { unsigned u; float f; } v; v.u = ((unsigned)u) << 16;
  return v.f;
}

// ---- CSR build ----
__global__ void count_kernel(const int* __restrict__ ei, int* __restrict__ cnt) {
  int e = blockIdx.x * 256 + threadIdx.x;
  if (e < N_EDGES) atomicAdd(&cnt[ei[N_EDGES + e]], 1);
}

__global__ __launch_bounds__(1024)
void scan_kernel(const int* __restrict__ cnt, int* __restrict__ csr, int* __restrict__ cursor) {
  __shared__ int partial[1024];
  const int tid = threadIdx.x;
  const int CHUNK = 49;  // 1024*49 >= 50000
  int base = tid * CHUNK;
  int s = 0;
  for (int i = 0; i < CHUNK; ++i) {
    int idx = base + i;
    if (idx < N_NODES) s += cnt[idx];
  }
  partial[tid] = s;
  __syncthreads();
  for (int off = 1; off < 1024; off <<= 1) {
    int v = (tid >= off) ? partial[tid - off] : 0;
    __syncthreads();
    partial[tid] += v;
    __syncthreads();
  }
  int run = partial[tid] - s;  // exclusive prefix
  for (int i = 0; i < CHUNK; ++i) {
    int idx = base + i;
    if (idx < N_NODES) {
      csr[idx] = run;
      cursor[idx] = run;
      run += cnt[idx];
    }
  }
  if (tid == 1023) csr[N_NODES] = run;
}

__global__ void rank_kernel(const int* __restrict__ ei, int* __restrict__ cursor,
                            int* __restrict__ pos) {
  int e = blockIdx.x * 256 + threadIdx.x;
  if (e < N_EDGES) pos[e] = atomicAdd(&cursor[ei[N_EDGES + e]], 1);
}

// pad eW1 [L][129][258] -> [L][129][264] (two 132-wide halves)
__global__ void prep_w1(const float* __restrict__ eW1, float* __restrict__ w1p) {
  int idx = blockIdx.x * blockDim.x + threadIdx.x;
  const int total = NLAYERS * EINDIM * H1;
  if (idx >= total) return;
  int j = idx % H1;
  int rest = idx / H1;
  int k = rest % EINDIM;
  int l = rest / EINDIM;
  int half = j / EINDIM;      // 0 or 1
  int c = j % EINDIM;         // 0..128
  w1p[(l * EINDIM + k) * W1P_STRIDE + half * W1P_HALF + c] = eW1[idx];
}

__global__ __launch_bounds__(256, 4)
void edge_kernel(const float* __restrict__ X,
                 const int* __restrict__ ei, const int* __restrict__ pos,
                 const float* __restrict__ w1p, const float* __restrict__ eb1,
                 const float* __restrict__ eW2, const float* __restrict__ eb2,
                 const float* __restrict__ cW1, const float* __restrict__ cb1,
                 const float* __restrict__ cW2, const float* __restrict__ cb2,
                 const float* __restrict__ cscale,
                 unsigned short* __restrict__ ms, float* __restrict__ mh4,
                 int layer)
{
  __shared__ float ein[32 * EINDIM];   // stride 129: conflict-free
  __shared__ float hs[32 * 130];       // half of h; stride 130: 2-way (free)
  __shared__ float ml[32 * 33];        // stride 33: conflict-free
  __shared__ float rel3[32 * 3];
  __shared__ float cpart[8 * 32];
  __shared__ int sd[2][32];
  __shared__ int pse[32];

  const int tid = threadIdx.x;
  const int e_loc = tid & 31;
  const int jg = tid >> 5;           // 0..7
  const int e0 = blockIdx.x * 32;

  if (tid < 32) {
    sd[0][tid] = ei[e0 + tid];            // src
    sd[1][tid] = ei[N_EDGES + e0 + tid];  // dst
    pse[tid] = pos[e0 + tid];
  }
  __syncthreads();

  // stage e_in = [feats[dst](64), feats[src](64), rel_dist]
  for (int idx = tid; idx < 32 * 128; idx += 256) {
    int e = idx >> 7;
    int k = idx & 127;
    int node = (k < 64) ? sd[1][e] : sd[0][e];
    ein[e * EINDIM + k] = X[node * XDIM + PDIM + (k & 63)];
  }
  if (tid < 32) {
    int s = sd[0][tid], d = sd[1][tid];
    float rx = X[s * XDIM + 0] - X[d * XDIM + 0];
    float ry = X[s * XDIM + 1] - X[d * XDIM + 1];
    float rz = X[s * XDIM + 2] - X[d * XDIM + 2];
    rel3[tid * 3 + 0] = rx;
    rel3[tid * 3 + 1] = ry;
    rel3[tid * 3 + 2] = rz;
    ein[tid * EINDIM + 128] = rx * rx + ry * ry + rz * rz;
  }
  __syncthreads();

  const float* W1 = w1p + layer * EINDIM * W1P_STRIDE;
  const float* B1 = eb1 + layer * H1;
  const float* W2 = eW2 + layer * H1 * MDIM;
  const float* B2 = eb2 + layer * MDIM;
  const int j4 = jg * 4;

  float macc[4];
  #pragma unroll
  for (int i = 0; i < 4; ++i) macc[i] = B2[j4 + i];

  // ---- phase 1+2 fused, split K in halves to halve hs LDS ----
  for (int half = 0; half < 2; ++half) {
    // h cols [half*129, half*129+129)
    for (int p = 0; p < 2; ++p) {
      const int c0 = jg * 16 + p * 8;               // 0..127
      const int jj = half * EINDIM + c0;            // bias index
      const int wcol = half * W1P_HALF + c0;        // padded W1 col
      float acc[8];
      #pragma unroll
      for (int i = 0; i < 8; ++i) acc[i] = B1[jj + i];
      #pragma unroll 2
      for (int k = 0; k < EINDIM; ++k) {
        float a = ein[e_loc * EINDIM + k];
        const float4 w0 = *reinterpret_cast<const float4*>(W1 + k * W1P_STRIDE + wcol);
        const float4 w1 = *reinterpret_cast<const float4*>(W1 + k * W1P_STRIDE + wcol + 4);
        acc[0] = fmaf(a, w0.x, acc[0]);
        acc[1] = fmaf(a, w0.y, acc[1]);
        acc[2] = fmaf(a, w0.z, acc[2]);
        acc[3] = fmaf(a, w0.w, acc[3]);
        acc[4] = fmaf(a, w1.x, acc[4]);
        acc[5] = fmaf(a, w1.y, acc[5]);
        acc[6] = fmaf(a, w1.z, acc[6]);
        acc[7] = fmaf(a, w1.w, acc[7]);
      }
      #pragma unroll
      for (int i = 0; i < 8; ++i) hs[e_loc * 130 + c0 + i] = fsilu(acc[i]);
    }
    if (jg == 0) {  // tail col c=128 of this half
      const int jj = half * EINDIM + 128;
      float acc = B1[jj];
      for (int k = 0; k < EINDIM; ++k)
        acc = fmaf(ein[e_loc * EINDIM + k], W1[k * W1P_STRIDE + half * W1P_HALF + 128], acc);
      hs[e_loc * 130 + 128] = fsilu(acc);
    }
    __syncthreads();

    // partial m accumulation over this half's 129 k values
    #pragma unroll 2
    for (int c = 0; c < EINDIM; ++c) {
      float hv = hs[e_loc * 130 + c];
      const int k = half * EINDIM + c;
      const float4 w = *reinterpret_cast<const float4*>(W2 + k * MDIM + j4);
      macc[0] = fmaf(hv, w.x, macc[0]);
      macc[1] = fmaf(hv, w.y, macc[1]);
      macc[2] = fmaf(hv, w.z, macc[2]);
      macc[3] = fmaf(hv, w.w, macc[3]);
    }
    __syncthreads();
  }

  // silu + store m_ij (bf16, CSR-sorted position) + keep in LDS for coor-MLP
  {
    ushort4 mu;
    #pragma unroll
    for (int i = 0; i < 4; ++i) {
      float mval = fsilu(macc[i]);
      ml[e_loc * 33 + j4 + i] = mval;
      reinterpret_cast<unsigned short*>(&mu)[i] = f2bf(mval);
    }
    *reinterpret_cast<ushort4*>(&ms[(size_t)pse[e_loc] * MDIM + j4]) = mu;
  }
  __syncthreads();

  // ---- phase 3: cw = tanh(silu(m @ cW1 + cb1) @ cW2 + cb2) ----
  const float* CW1 = cW1 + layer * MDIM * CH;
  const float* CB1 = cb1 + layer * CH;
  const float* CW2 = cW2 + layer * CH;
  const int j16 = jg * 16;
  float cacc[16];
  #pragma unroll
  for (int i = 0; i < 16; ++i) cacc[i] = CB1[j16 + i];
  for (int k = 0; k < MDIM; ++k) {
    float mvv = ml[e_loc * 33 + k];
    #pragma unroll
    for (int i = 0; i < 16; i += 4) {
      const float4 w = *reinterpret_cast<const float4*>(CW1 + k * CH + j16 + i);
      cacc[i + 0] = fmaf(mvv, w.x, cacc[i + 0]);
      cacc[i + 1] = fmaf(mvv, w.y, cacc[i + 1]);
      cacc[i + 2] = fmaf(mvv, w.z, cacc[i + 2]);
      cacc[i + 3] = fmaf(mvv, w.w, cacc[i + 3]);
    }
  }
  float part = 0.0f;
  #pragma unroll
  for (int i = 0; i < 16; ++i) part += fsilu(cacc[i]) * CW2[j16 + i];
  cpart[jg * 32 + e_loc] = part;
  __syncthreads();

  if (tid < 32) {
    float s = cb2[layer];
    #pragma unroll
    for (int g = 0; g < 8; ++g) s += cpart[g * 32 + tid];
    float cw = tanhf(s);
    float dist = ein[tid * EINDIM + 128];
    float nrm = sqrtf(dist);
    float fac = cw * cscale[layer] / fmaxf(nrm, 1e-8f);
    int p = pse[tid];
    *reinterpret_cast<float4*>(&mh4[(size_t)p * 4]) =
        make_float4(fac * rel3[tid * 3 + 0], fac * rel3[tid * 3 + 1],
                    fac * rel3[tid * 3 + 2], 0.0f);
  }
}

__global__ __launch_bounds__(256)
void gather_node_kernel(const float* __restrict__ Xin,
                        const unsigned short* __restrict__ ms,
                        const float* __restrict__ mh4,
                        const int* __restrict__ csr,
                        const float* __restrict__ nW1, const float* __restrict__ nb1,
                        const float* __restrict__ nW2, const float* __restrict__ nb2,
                        float* __restrict__ Xout, int layer)
{
  __shared__ float nin[4][97];
  __shared__ float hn[4][NH + 1];
  __shared__ float mhs[4][3];
  const int tid = threadIdx.x;
  const int w = tid >> 6;
  const int lane = tid & 63;
  const int n = blockIdx.x * 4 + w;

  const int off = csr[n];
  const int end = csr[n + 1];

  // gather m_i (sum of bf16 rows, contiguous in sorted order)
  {
    const int col = lane & 31;
    const int hh = lane >> 5;
    float s = 0.0f;
    for (int r = off + hh; r < end; r += 2)
      s += bf2f(ms[(size_t)r * MDIM + col]);
    s += __shfl_xor(s, 32, 64);
    if (hh == 0) nin[w][FDIM + col] = s;
  }
  // gather mhat_i (3 floats, stride-4 rows)
  {
    const int mc = lane & 3;
    const int mr = lane >> 2;  // 0..15
    float t = 0.0f;
    for (int r = off + mr; r < end; r += 16)
      t += mh4[(size_t)r * 4 + mc];
    t += __shfl_xor(t, 4, 64);
    t += __shfl_xor(t, 8, 64);
    t += __shfl_xor(t, 16, 64);
    t += __shfl_xor(t, 32, 64);
    if (lane < 3) mhs[w][lane] = t;
  }
  nin[w][lane] = Xin[n * XDIM + PDIM + lane];
  __syncthreads();

  const float* W1 = nW1 + layer * (FDIM + MDIM) * NH;
  const float* B1 = nb1 + layer * NH;
  float a0 = B1[lane];
  float a1 = B1[lane + 64];
  #pragma unroll 4
  for (int k = 0; k < FDIM + MDIM; ++k) {
    float v = nin[w][k];
    a0 = fmaf(v, W1[k * NH + lane], a0);
    a1 = fmaf(v, W1[k * NH + lane + 64], a1);
  }
  hn[w][lane] = fsilu(a0);
  hn[w][lane + 64] = fsilu(a1);
  __syncthreads();

  const float* W2 = nW2 + layer * NH * FDIM;
  float acc = nb2[layer * FDIM + lane];
  #pragma unroll 4
  for (int k = 0; k < NH; ++k)
    acc = fmaf(hn[w][k], W2[k * FDIM + lane], acc);

  float feat = Xin[n * XDIM + PDIM + lane];
  Xout[n * XDIM + PDIM + lane] = feat + acc;
  if (lane < PDIM)
    Xout[n * XDIM + lane] = Xin[n * XDIM + lane] + mhs[w][lane];
}

extern "C" void kernel_launch(void* const* d_in, const int* in_sizes, int n_in,
                              void* d_out, int out_size, void* d_ws, size_t ws_size,
                              hipStream_t stream) {
  const float* x      = (const float*)d_in[0];
  const int*   ei     = (const int*)d_in[1];
  const float* eW1    = (const float*)d_in[2];
  const float* eb1    = (const float*)d_in[3];
  const float* eW2    = (const float*)d_in[4];
  const float* eb2    = (const float*)d_in[5];
  const float* cW1    = (const float*)d_in[6];
  const float* cb1    = (const float*)d_in[7];
  const float* cW2    = (const float*)d_in[8];
  const float* cb2    = (const float*)d_in[9];
  const float* nW1    = (const float*)d_in[10];
  const float* nb1    = (const float*)d_in[11];
  const float* nW2    = (const float*)d_in[12];
  const float* nb2    = (const float*)d_in[13];
  const float* cscale = (const float*)d_in[14];

  float* ws     = (float*)d_ws;
  float* X1     = ws;                                   // N*67
  float* mh4    = X1 + N_NODES * XDIM;                  // E*4
  float* w1p    = mh4 + (size_t)N_EDGES * 4;            // L*129*264
  int*   csr    = (int*)(w1p + NLAYERS * EINDIM * W1P_STRIDE);  // N+2 (pad to even)
  int*   cursor = csr + N_NODES + 2;                    // N
  int*   cnt    = cursor + N_NODES;                     // N
  int*   pos    = cnt + N_NODES;                        // E
  unsigned short* ms = (unsigned short*)(pos + N_EDGES);  // E*32 bf16

  // one-time CSR build (pos is layer-independent)
  hipMemsetAsync(cnt, 0, N_NODES * sizeof(int), stream);
  count_kernel<<<(N_EDGES + 255) / 256, 256, 0, stream>>>(ei, cnt);
  scan_kernel<<<1, 1024, 0, stream>>>(cnt, csr, cursor);
  rank_kernel<<<(N_EDGES + 255) / 256, 256, 0, stream>>>(ei, cursor, pos);
  prep_w1<<<(NLAYERS * EINDIM * H1 + 255) / 256, 256, 0, stream>>>(eW1, w1p);

  for (int l = 0; l < NLAYERS; ++l) {
    const float* Xin = (l == 0) ? x : X1;
    float* Xout = (l == 0) ? X1 : (float*)d_out;
    edge_kernel<<<N_EDGES / 32, 256, 0, stream>>>(
        Xin, ei, pos, w1p, eb1, eW2, eb2, cW1, cb1, cW2, cb2, cscale, ms, mh4, l);
    gather_node_kernel<<<N_NODES / 4, 256, 0, stream>>>(
        Xin, ms, mh4, csr, nW1, nb1, nW2, nb2, Xout, l);
  }
}

// Round 3
// 1158.975 us; speedup vs baseline: 9.6793x; 9.6793x over previous
//
#include <hip/hip_runtime.h>

#define N_NODES 50000
#define N_EDGES 800000
#define PDIM 3
#define FDIM 64
#define MDIM 32
#define NLAYERS 2
#define EINDIM 129
#define H1 258          // 2*EIN
#define CH 128          // 4*M
#define NH 128          // 2*F
#define XDIM 67         // P+F
#define K1P 136         // e_in LDS k-stride (128 + 8 pad)
#define H1T 288         // padded h cols (18 tiles of 16)
#define HSTR 296        // h LDS row stride (bf16)
#define MLSTR 40        // ml LDS row stride (bf16)
#define W1T_K 136       // w1t k-dim (128 + 8 pad)

typedef __attribute__((ext_vector_type(8))) short short8;
typedef __attribute__((ext_vector_type(4))) float f32x4;

__device__ __forceinline__ float fsilu(float x) {
  return x / (1.0f + __expf(-x));
}

__device__ __forceinline__ unsigned short f2bf(float f) {
  union { float f; unsigned u; } v; v.f = f;
  unsigned r = v.u + 0x7FFF + ((v.u >> 16) & 1);  // RNE
  return (unsigned short)(r >> 16);
}

__device__ __forceinline__ float bf2f(unsigned short u) {
  union { unsigned u; float f; } v; v.u = ((unsigned)u) << 16;
  return v.f;
}

// ---- CSR build ----
__global__ void count_kernel(const int* __restrict__ ei, int* __restrict__ cnt) {
  int e = blockIdx.x * 256 + threadIdx.x;
  if (e < N_EDGES) atomicAdd(&cnt[ei[N_EDGES + e]], 1);
}

__global__ __launch_bounds__(1024)
void scan_kernel(const int* __restrict__ cnt, int* __restrict__ csr, int* __restrict__ cursor) {
  __shared__ int partial[1024];
  const int tid = threadIdx.x;
  const int CHUNK = 49;
  int base = tid * CHUNK;
  int s = 0;
  for (int i = 0; i < CHUNK; ++i) {
    int idx = base + i;
    if (idx < N_NODES) s += cnt[idx];
  }
  partial[tid] = s;
  __syncthreads();
  for (int off = 1; off < 1024; off <<= 1) {
    int v = (tid >= off) ? partial[tid - off] : 0;
    __syncthreads();
    partial[tid] += v;
    __syncthreads();
  }
  int run = partial[tid] - s;
  for (int i = 0; i < CHUNK; ++i) {
    int idx = base + i;
    if (idx < N_NODES) {
      csr[idx] = run;
      cursor[idx] = run;
      run += cnt[idx];
    }
  }
  if (tid == 1023) csr[N_NODES] = run;
}

__global__ void rank_kernel(const int* __restrict__ ei, int* __restrict__ cursor,
                            int* __restrict__ pos) {
  int e = blockIdx.x * 256 + threadIdx.x;
  if (e < N_EDGES) pos[e] = atomicAdd(&cursor[ei[N_EDGES + e]], 1);
}

// ---- weight prep: bf16 transposed+padded copies ----
// w1t [L][288 j][136 k] (k<128 real, rest 0; j>=258 -> 0)
// w2t [L][32 n][288 k]  (k<258 real)
// cw1t[L][128 n][32 k]
__global__ void prep_weights(const float* __restrict__ eW1, const float* __restrict__ eW2,
                             const float* __restrict__ cW1,
                             unsigned short* __restrict__ w1t, unsigned short* __restrict__ w2t,
                             unsigned short* __restrict__ cw1t) {
  int idx = blockIdx.x * 256 + threadIdx.x;
  const int n1 = NLAYERS * H1T * W1T_K;
  const int n2 = NLAYERS * MDIM * H1T;
  const int n3 = NLAYERS * CH * MDIM;
  if (idx < n1) {
    int k = idx % W1T_K;
    int rest = idx / W1T_K;
    int j = rest % H1T;
    int l = rest / H1T;
    float v = (k < 128 && j < H1) ? eW1[(l * EINDIM + k) * H1 + j] : 0.0f;
    w1t[idx] = f2bf(v);
  } else if (idx < n1 + n2) {
    int t = idx - n1;
    int k = t % H1T;
    int rest = t / H1T;
    int n = rest % MDIM;
    int l = rest / MDIM;
    float v = (k < H1) ? eW2[(l * H1 + k) * MDIM + n] : 0.0f;
    w2t[t] = f2bf(v);
  } else if (idx < n1 + n2 + n3) {
    int t = idx - n1 - n2;
    int k = t % MDIM;
    int rest = t / MDIM;
    int n = rest % CH;
    int l = rest / CH;
    cw1t[t] = f2bf(cW1[(l * MDIM + k) * CH + n]);
  }
}

__global__ __launch_bounds__(256)
void edge_mfma_kernel(const float* __restrict__ X,
                      const int* __restrict__ ei, const int* __restrict__ pos,
                      const unsigned short* __restrict__ w1t,
                      const float* __restrict__ eW1, const float* __restrict__ eb1,
                      const unsigned short* __restrict__ w2t, const float* __restrict__ eb2,
                      const unsigned short* __restrict__ cw1t, const float* __restrict__ cb1,
                      const float* __restrict__ cW2, const float* __restrict__ cb2,
                      const float* __restrict__ cscale,
                      unsigned short* __restrict__ ms, float* __restrict__ mh4,
                      int layer)
{
  __shared__ unsigned short einLds[64 * K1P];   // 17.4 KB
  __shared__ unsigned short hLds[64 * HSTR];    // 37.9 KB
  __shared__ unsigned short mlLds[64 * MLSTR];  // 5.1 KB
  __shared__ float rel3[64 * 3];
  __shared__ float distLds[64];
  __shared__ float cwLds[64];
  __shared__ int sdS[64], sdD[64], pse[64];

  const int tid = threadIdx.x;
  const int lane = tid & 63;
  const int wid = tid >> 6;
  const int ln15 = lane & 15;   // tile col
  const int kg = lane >> 4;     // k-group 0..3
  const int e0 = blockIdx.x * 64;

  if (tid < 64) {
    int s = ei[e0 + tid];
    int d = ei[N_EDGES + e0 + tid];
    sdS[tid] = s; sdD[tid] = d;
    pse[tid] = pos[e0 + tid];
    float rx = X[s * XDIM + 0] - X[d * XDIM + 0];
    float ry = X[s * XDIM + 1] - X[d * XDIM + 1];
    float rz = X[s * XDIM + 2] - X[d * XDIM + 2];
    rel3[tid * 3 + 0] = rx;
    rel3[tid * 3 + 1] = ry;
    rel3[tid * 3 + 2] = rz;
    distLds[tid] = rx * rx + ry * ry + rz * rz;
  }
  __syncthreads();

  // stage e_in bf16: [64 e][128 k] = [feats[dst] | feats[src]]
  #pragma unroll
  for (int it = 0; it < 4; ++it) {
    int idx = tid + it * 256;       // 0..1023
    int e = idx >> 4;
    int c = idx & 15;               // 8-col chunk
    int node = (c < 8) ? sdD[e] : sdS[e];
    const float* src = X + node * XDIM + PDIM + (c & 7) * 8;
    short8 v;
    #pragma unroll
    for (int i = 0; i < 8; ++i) v[i] = (short)f2bf(src[i]);
    *(short8*)&einLds[e * K1P + c * 8] = v;
  }
  __syncthreads();

  // ---- phase B: h[64x288] = silu(e_in @ W1 + b1 + dist*W1row128) ----
  const unsigned short* W1T = w1t + layer * H1T * W1T_K;
  const float* B1 = eb1 + layer * H1;
  const float* W1r128 = eW1 + ((size_t)layer * EINDIM + 128) * H1;
  for (int jt = wid; jt < 18; jt += 4) {
    int j = jt * 16 + ln15;
    float bj = (j < H1) ? B1[j] : 0.0f;
    float wj = (j < H1) ? W1r128[j] : 0.0f;
    f32x4 acc[4];
    #pragma unroll
    for (int mt = 0; mt < 4; ++mt) {
      #pragma unroll
      for (int r = 0; r < 4; ++r)
        acc[mt][r] = fmaf(distLds[mt * 16 + kg * 4 + r], wj, bj);
    }
    #pragma unroll
    for (int ks = 0; ks < 4; ++ks) {
      short8 b = *(const short8*)&W1T[j * W1T_K + kg * 8 + ks * 32];
      #pragma unroll
      for (int mt = 0; mt < 4; ++mt) {
        short8 a = *(const short8*)&einLds[(mt * 16 + ln15) * K1P + kg * 8 + ks * 32];
        acc[mt] = __builtin_amdgcn_mfma_f32_16x16x32_bf16(a, b, acc[mt], 0, 0, 0);
      }
    }
    #pragma unroll
    for (int mt = 0; mt < 4; ++mt)
      #pragma unroll
      for (int r = 0; r < 4; ++r) {
        int m = mt * 16 + kg * 4 + r;
        hLds[m * HSTR + jt * 16 + ln15] = f2bf(fsilu(acc[mt][r]));
      }
  }
  __syncthreads();

  // ---- phase C: m[64x32] = silu(h @ W2 + b2) ----
  const unsigned short* W2T = w2t + layer * MDIM * H1T;
  const float* B2 = eb2 + layer * MDIM;
  {
    int nt = wid >> 1;
    int mtb = (wid & 1) * 2;
    int n = nt * 16 + ln15;
    float b2v = B2[n];
    f32x4 acc0 = {b2v, b2v, b2v, b2v};
    f32x4 acc1 = {b2v, b2v, b2v, b2v};
    #pragma unroll
    for (int ks = 0; ks < 9; ++ks) {
      short8 b = *(const short8*)&W2T[n * H1T + kg * 8 + ks * 32];
      short8 a0 = *(const short8*)&hLds[(mtb * 16 + ln15) * HSTR + kg * 8 + ks * 32];
      short8 a1 = *(const short8*)&hLds[((mtb + 1) * 16 + ln15) * HSTR + kg * 8 + ks * 32];
      acc0 = __builtin_amdgcn_mfma_f32_16x16x32_bf16(a0, b, acc0, 0, 0, 0);
      acc1 = __builtin_amdgcn_mfma_f32_16x16x32_bf16(a1, b, acc1, 0, 0, 0);
    }
    #pragma unroll
    for (int r = 0; r < 4; ++r) {
      int m0 = mtb * 16 + kg * 4 + r;
      int m1 = (mtb + 1) * 16 + kg * 4 + r;
      mlLds[m0 * MLSTR + n] = f2bf(fsilu(acc0[r]));
      mlLds[m1 * MLSTR + n] = f2bf(fsilu(acc1[r]));
    }
  }
  __syncthreads();

  // write m_ij rows (coalesced 64B per edge, CSR-sorted position)
  {
    int r = tid >> 2, seg = tid & 3;
    short8 v = *(const short8*)&mlLds[r * MLSTR + seg * 8];
    *(short8*)&ms[(size_t)pse[r] * MDIM + seg * 8] = v;
  }

  // ---- phase D: cw = tanh(silu(m @ cW1 + cb1) @ cW2 + cb2) ----
  const unsigned short* CW1T = cw1t + layer * CH * MDIM;
  const float* CB1 = cb1 + layer * CH;
  const float* CW2v = cW2 + layer * CH;
  {
    int mt = wid;
    short8 a = *(const short8*)&mlLds[(mt * 16 + ln15) * MLSTR + kg * 8];
    float psum[4] = {0.f, 0.f, 0.f, 0.f};
    #pragma unroll
    for (int nt = 0; nt < 8; ++nt) {
      int n2 = nt * 16 + ln15;
      short8 b = *(const short8*)&CW1T[n2 * MDIM + kg * 8];
      float cb = CB1[n2];
      f32x4 acc = {cb, cb, cb, cb};
      acc = __builtin_amdgcn_mfma_f32_16x16x32_bf16(a, b, acc, 0, 0, 0);
      float w2v = CW2v[n2];
      #pragma unroll
      for (int r = 0; r < 4; ++r) psum[r] += fsilu(acc[r]) * w2v;
    }
    #pragma unroll
    for (int off = 1; off < 16; off <<= 1) {
      #pragma unroll
      for (int r = 0; r < 4; ++r) psum[r] += __shfl_xor(psum[r], off, 64);
    }
    if (ln15 == 0) {
      #pragma unroll
      for (int r = 0; r < 4; ++r) cwLds[mt * 16 + kg * 4 + r] = psum[r];
    }
  }
  __syncthreads();

  if (tid < 64) {
    float cw = tanhf(cwLds[tid] + cb2[layer]);
    float fac = cw * cscale[layer] / fmaxf(sqrtf(distLds[tid]), 1e-8f);
    *(float4*)&mh4[(size_t)pse[tid] * 4] =
        make_float4(fac * rel3[tid * 3 + 0], fac * rel3[tid * 3 + 1],
                    fac * rel3[tid * 3 + 2], 0.0f);
  }
}

__global__ __launch_bounds__(256)
void gather_node_kernel(const float* __restrict__ Xin,
                        const unsigned short* __restrict__ ms,
                        const float* __restrict__ mh4,
                        const int* __restrict__ csr,
                        const float* __restrict__ nW1, const float* __restrict__ nb1,
                        const float* __restrict__ nW2, const float* __restrict__ nb2,
                        float* __restrict__ Xout, int layer)
{
  __shared__ float nin[4][97];
  __shared__ float hn[4][NH + 1];
  __shared__ float mhs[4][3];
  const int tid = threadIdx.x;
  const int w = tid >> 6;
  const int lane = tid & 63;
  const int n = blockIdx.x * 4 + w;

  const int off = csr[n];
  const int end = csr[n + 1];

  {
    const int col = lane & 31;
    const int hh = lane >> 5;
    float s = 0.0f;
    for (int r = off + hh; r < end; r += 2)
      s += bf2f(ms[(size_t)r * MDIM + col]);
    s += __shfl_xor(s, 32, 64);
    if (hh == 0) nin[w][FDIM + col] = s;
  }
  {
    const int mc = lane & 3;
    const int mr = lane >> 2;
    float t = 0.0f;
    for (int r = off + mr; r < end; r += 16)
      t += mh4[(size_t)r * 4 + mc];
    t += __shfl_xor(t, 4, 64);
    t += __shfl_xor(t, 8, 64);
    t += __shfl_xor(t, 16, 64);
    t += __shfl_xor(t, 32, 64);
    if (lane < 3) mhs[w][lane] = t;
  }
  nin[w][lane] = Xin[n * XDIM + PDIM + lane];
  __syncthreads();

  const float* W1 = nW1 + layer * (FDIM + MDIM) * NH;
  const float* B1 = nb1 + layer * NH;
  float a0 = B1[lane];
  float a1 = B1[lane + 64];
  #pragma unroll 4
  for (int k = 0; k < FDIM + MDIM; ++k) {
    float v = nin[w][k];
    a0 = fmaf(v, W1[k * NH + lane], a0);
    a1 = fmaf(v, W1[k * NH + lane + 64], a1);
  }
  hn[w][lane] = fsilu(a0);
  hn[w][lane + 64] = fsilu(a1);
  __syncthreads();

  const float* W2 = nW2 + layer * NH * FDIM;
  float acc = nb2[layer * FDIM + lane];
  #pragma unroll 4
  for (int k = 0; k < NH; ++k)
    acc = fmaf(hn[w][k], W2[k * FDIM + lane], acc);

  float feat = Xin[n * XDIM + PDIM + lane];
  Xout[n * XDIM + PDIM + lane] = feat + acc;
  if (lane < PDIM)
    Xout[n * XDIM + lane] = Xin[n * XDIM + lane] + mhs[w][lane];
}

extern "C" void kernel_launch(void* const* d_in, const int* in_sizes, int n_in,
                              void* d_out, int out_size, void* d_ws, size_t ws_size,
                              hipStream_t stream) {
  const float* x      = (const float*)d_in[0];
  const int*   ei     = (const int*)d_in[1];
  const float* eW1    = (const float*)d_in[2];
  const float* eb1    = (const float*)d_in[3];
  const float* eW2    = (const float*)d_in[4];
  const float* eb2    = (const float*)d_in[5];
  const float* cW1    = (const float*)d_in[6];
  const float* cb1    = (const float*)d_in[7];
  const float* cW2    = (const float*)d_in[8];
  const float* cb2    = (const float*)d_in[9];
  const float* nW1    = (const float*)d_in[10];
  const float* nb1    = (const float*)d_in[11];
  const float* nW2    = (const float*)d_in[12];
  const float* nb2    = (const float*)d_in[13];
  const float* cscale = (const float*)d_in[14];

  float* ws     = (float*)d_ws;
  float* X1     = ws;                                   // N*67 floats
  float* mh4    = X1 + N_NODES * XDIM;                  // E*4 floats
  int*   csr    = (int*)(mh4 + (size_t)N_EDGES * 4);    // N+2
  int*   cursor = csr + N_NODES + 2;                    // N
  int*   cnt    = cursor + N_NODES;                     // N
  int*   pos    = cnt + N_NODES;                        // E
  unsigned short* w1t  = (unsigned short*)(pos + N_EDGES);
  unsigned short* w2t  = w1t + NLAYERS * H1T * W1T_K;
  unsigned short* cw1t = w2t + NLAYERS * MDIM * H1T;
  unsigned short* ms   = cw1t + NLAYERS * CH * MDIM;    // E*32 bf16

  hipMemsetAsync(cnt, 0, N_NODES * sizeof(int), stream);
  count_kernel<<<(N_EDGES + 255) / 256, 256, 0, stream>>>(ei, cnt);
  scan_kernel<<<1, 1024, 0, stream>>>(cnt, csr, cursor);
  rank_kernel<<<(N_EDGES + 255) / 256, 256, 0, stream>>>(ei, cursor, pos);
  {
    const int total = NLAYERS * (H1T * W1T_K + MDIM * H1T + CH * MDIM);
    prep_weights<<<(total + 255) / 256, 256, 0, stream>>>(eW1, eW2, cW1, w1t, w2t, cw1t);
  }

  for (int l = 0; l < NLAYERS; ++l) {
    const float* Xin = (l == 0) ? x : X1;
    float* Xout = (l == 0) ? X1 : (float*)d_out;
    edge_mfma_kernel<<<N_EDGES / 64, 256, 0, stream>>>(
        Xin, ei, pos, w1t, eW1, eb1, w2t, eb2, cw1t, cb1, cW2, cb2, cscale, ms, mh4, l);
    gather_node_kernel<<<N_NODES / 4, 256, 0, stream>>>(
        Xin, ms, mh4, csr, nW1, nb1, nW2, nb2, Xout, l);
  }
}